// Round 7
// baseline (931.812 us; speedup 1.0000x reference)
//
#include <hip/hip_runtime.h>
#include <cstdint>
#include <cstddef>

// Problem constants (from reference setup_inputs)
#define N_NODES 50000
#define FDIM    256
#define HDIM    64
#define E_EDGES 1600000
#define BATCH_N 1000000
#define TOT2    (2 * N_NODES)           // 2 graphs * N counts
#define S0B     ((TOT2 + 1023) / 1024)  // 98 level-0 scan blocks (4 elems/thread)

// ---------------------------------------------------------------------------
// K1: tiled fp32 GEMM  C[M x 64] = A[M x 256] @ B[256 x 64]
// Optional fused attention scalars: ssrc[m] = C[m,:].a[:64], sdst = C[m,:].a[64:]
// ---------------------------------------------------------------------------
__global__ __launch_bounds__(256) void gemm_k256(const float* __restrict__ A,
                                                 const float* __restrict__ B,
                                                 float* __restrict__ C, int M,
                                                 const float* __restrict__ a_att,
                                                 float* __restrict__ ssrc,
                                                 float* __restrict__ sdst) {
  __shared__ float As[64][68];
  __shared__ float Bs[64][64];
  const int t  = threadIdx.x;
  const int tx = t & 15;        // N direction (cols tx*4..+3)
  const int ty = t >> 4;        // M direction (rows ty*4..+3)
  const int m0 = blockIdx.x * 64;

  float acc[4][4] = {};

  for (int kc = 0; kc < 4; ++kc) {
    __syncthreads();
#pragma unroll
    for (int i = 0; i < 4; ++i) {
      int f = t + i * 256;            // 0..1023
      int row = f >> 4, c4 = f & 15;  // row in tile, float4-col in chunk
      int mg = m0 + row; mg = (mg < M) ? mg : (M - 1);
      float4 va = *(const float4*)(A + (size_t)mg * FDIM + kc * 64 + c4 * 4);
      As[c4 * 4 + 0][row] = va.x;
      As[c4 * 4 + 1][row] = va.y;
      As[c4 * 4 + 2][row] = va.z;
      As[c4 * 4 + 3][row] = va.w;
      *(float4*)(&Bs[row][c4 * 4]) =
          *(const float4*)(B + (size_t)(kc * 64 + row) * HDIM + c4 * 4);
    }
    __syncthreads();
#pragma unroll 4
    for (int k = 0; k < 64; ++k) {
      float4 a = *(const float4*)(&As[k][ty * 4]);
      float4 b = *(const float4*)(&Bs[k][tx * 4]);
      acc[0][0] = fmaf(a.x, b.x, acc[0][0]);
      acc[0][1] = fmaf(a.x, b.y, acc[0][1]);
      acc[0][2] = fmaf(a.x, b.z, acc[0][2]);
      acc[0][3] = fmaf(a.x, b.w, acc[0][3]);
      acc[1][0] = fmaf(a.y, b.x, acc[1][0]);
      acc[1][1] = fmaf(a.y, b.y, acc[1][1]);
      acc[1][2] = fmaf(a.y, b.z, acc[1][2]);
      acc[1][3] = fmaf(a.y, b.w, acc[1][3]);
      acc[2][0] = fmaf(a.z, b.x, acc[2][0]);
      acc[2][1] = fmaf(a.z, b.y, acc[2][1]);
      acc[2][2] = fmaf(a.z, b.z, acc[2][2]);
      acc[2][3] = fmaf(a.z, b.w, acc[2][3]);
      acc[3][0] = fmaf(a.w, b.x, acc[3][0]);
      acc[3][1] = fmaf(a.w, b.y, acc[3][1]);
      acc[3][2] = fmaf(a.w, b.z, acc[3][2]);
      acc[3][3] = fmaf(a.w, b.w, acc[3][3]);
    }
  }

#pragma unroll
  for (int i = 0; i < 4; ++i) {
    int m = m0 + ty * 4 + i;
    if (m < M)
      *(float4*)(C + (size_t)m * HDIM + tx * 4) =
          make_float4(acc[i][0], acc[i][1], acc[i][2], acc[i][3]);
  }

  if (a_att) {
    float4 aa1 = *(const float4*)(a_att + tx * 4);
    float4 aa2 = *(const float4*)(a_att + HDIM + tx * 4);
#pragma unroll
    for (int i = 0; i < 4; ++i) {
      float s1 = acc[i][0] * aa1.x + acc[i][1] * aa1.y +
                 acc[i][2] * aa1.z + acc[i][3] * aa1.w;
      float s2 = acc[i][0] * aa2.x + acc[i][1] * aa2.y +
                 acc[i][2] * aa2.z + acc[i][3] * aa2.w;
#pragma unroll
      for (int d = 1; d < 16; d <<= 1) {
        s1 += __shfl_xor(s1, d);
        s2 += __shfl_xor(s2, d);
      }
      int m = m0 + ty * 4 + i;
      if (tx == 0 && m < M) { ssrc[m] = s1; sdst[m] = s2; }
    }
  }
}

// ---------------------------------------------------------------------------
// K2: per-edge degree histogram, both graphs (grid.y). NT edge reads.
// ---------------------------------------------------------------------------
__global__ void edge_count2(const int2* __restrict__ ue,
                            const int2* __restrict__ be,
                            int* __restrict__ cnt) {
  int e = blockIdx.x * blockDim.x + threadIdx.x;
  if (e >= E_EDGES) return;
  const long long* ep = (const long long*)(blockIdx.y ? be : ue);
  long long ev = __builtin_nontemporal_load(ep + e);
  int src = (int)(ev & 0xffffffff);
  atomicAdd(&cnt[blockIdx.y * N_NODES + src], 1);
}

// ---------------------------------------------------------------------------
// K3a/b/c: 3-level exclusive scan over the 100k count array (in place).
// ---------------------------------------------------------------------------
__global__ __launch_bounds__(256) void scan0(int* __restrict__ cnt,
                                             int* __restrict__ psum) {
  __shared__ int sh[256];
  int t  = threadIdx.x;
  int i0 = blockIdx.x * 1024 + t * 4;
  int v0 = 0, v1 = 0, v2 = 0, v3 = 0;
  if (i0 + 3 < TOT2) {
    int4 v = *(const int4*)(cnt + i0);
    v0 = v.x; v1 = v.y; v2 = v.z; v3 = v.w;
  } else if (i0 < TOT2) {
    v0 = cnt[i0];
    if (i0 + 1 < TOT2) v1 = cnt[i0 + 1];
    if (i0 + 2 < TOT2) v2 = cnt[i0 + 2];
  }
  int s = v0 + v1 + v2 + v3;
  sh[t] = s;
  __syncthreads();
#pragma unroll
  for (int d = 1; d < 256; d <<= 1) {
    int tv = (t >= d) ? sh[t - d] : 0;
    __syncthreads();
    sh[t] += tv;
    __syncthreads();
  }
  int excl = sh[t] - s;
  if (i0 < TOT2) {
    cnt[i0] = excl;
    if (i0 + 1 < TOT2) cnt[i0 + 1] = excl + v0;
    if (i0 + 2 < TOT2) cnt[i0 + 2] = excl + v0 + v1;
    if (i0 + 3 < TOT2) cnt[i0 + 3] = excl + v0 + v1 + v2;
  }
  if (t == 255) psum[blockIdx.x] = sh[255];
}

__global__ __launch_bounds__(128) void scan1(int* __restrict__ psum,
                                             int* __restrict__ S) {
  __shared__ int sh[128];
  int t = threadIdx.x;
  int v = (t < S0B) ? psum[t] : 0;
  sh[t] = v;
  __syncthreads();
#pragma unroll
  for (int d = 1; d < 128; d <<= 1) {
    int tv = (t >= d) ? sh[t - d] : 0;
    __syncthreads();
    sh[t] += tv;
    __syncthreads();
  }
  if (t < S0B) psum[t] = sh[t] - v;   // exclusive
  if (t == 127) S[TOT2] = sh[127];    // grand total (= 2*E_EDGES)
}

__global__ __launch_bounds__(256) void scan2(int* __restrict__ cnt,
                                             int* __restrict__ S,
                                             const int* __restrict__ psum) {
  int i = blockIdx.x * 256 + threadIdx.x;
  if (i < TOT2) {
    int val = cnt[i] + psum[i >> 10];
    S[i]   = val;   // segment starts
    cnt[i] = val;   // reused as bump cursors
  }
}

// ---------------------------------------------------------------------------
// K4: CSR scatter of PACKED 4-byte records: dst | type<<16.
// (w is recomputed in aggregate — halves scatter store line-evictions.)
// ---------------------------------------------------------------------------
__global__ void edge_pack_scatter(const int2* __restrict__ ue,
                                  const int2* __restrict__ be,
                                  const int* __restrict__ bet,
                                  int* __restrict__ cur,
                                  int* __restrict__ recbuf) {
  int e = blockIdx.x * blockDim.x + threadIdx.x;
  if (e >= E_EDGES) return;
  int graph = blockIdx.y;
  const long long* ep = (const long long*)(graph ? be : ue);
  long long ev = __builtin_nontemporal_load(ep + e);
  int src = (int)(ev & 0xffffffff);
  int dst = (int)(ev >> 32);
  int rec = dst;
  if (graph) rec |= __builtin_nontemporal_load(bet + e) << 16;
  int pos = atomicAdd(&cur[graph * N_NODES + src], 1);
  recbuf[pos] = rec;
}

// ---------------------------------------------------------------------------
// K5: gather aggregation; w recomputed in-kernel.
// w = sigmoid(leaky_relu(ssrc[n] + sdst[dst], 0.2) [+ gw[type]])
// x2[n] = (sum w*x1[dst]) / max(sum w, 1e-8)
// One wave per node, 4 records in flight, float4 row slices.
// ---------------------------------------------------------------------------
__global__ void aggregate2(const int* __restrict__ S,
                           const int* __restrict__ recbuf,
                           const float* __restrict__ ssrc_u,
                           const float* __restrict__ sdst_u,
                           const float* __restrict__ x1u,
                           float* __restrict__ x2u,
                           const float* __restrict__ ssrc_b,
                           const float* __restrict__ sdst_b,
                           const float* __restrict__ x1b,
                           float* __restrict__ x2b,
                           const float* __restrict__ gw) {
  int wid  = (blockIdx.x * blockDim.x + threadIdx.x) >> 6;
  int lane = threadIdx.x & 63;
  if (wid >= N_NODES) return;
  int graph = blockIdx.y;
  const float* sdst = graph ? sdst_b : sdst_u;
  const float* x1   = graph ? x1b : x1u;
  float*       x2   = graph ? x2b : x2u;
  float s_src = graph ? ssrc_b[wid] : ssrc_u[wid];
  float g0 = gw[0], g1 = gw[1], g2 = gw[2];
  const int q  = lane & 15;
  const int es = lane >> 4;
  int beg = S[graph * N_NODES + wid];
  int end = S[graph * N_NODES + wid + 1];  // scan continuity
  float4 acc = make_float4(0.f, 0.f, 0.f, 0.f);
  float wsum = 0.f;
  const float4* x1v = (const float4*)x1;
  for (int j = beg; j < end; j += 4) {
    int jj = j + es;
    bool valid = jj < end;
    int rec = recbuf[valid ? jj : beg];
    int dst = rec & 0xffff;
    float x = s_src + sdst[dst];
    x = (x >= 0.f) ? x : 0.2f * x;
    if (graph) {
      int ty = rec >> 16;
      x += (ty == 0) ? g0 : ((ty == 1) ? g1 : g2);
    }
    float w = valid ? (1.f / (1.f + __expf(-x))) : 0.f;
    float4 v = x1v[(size_t)dst * 16 + q];
    acc.x = fmaf(w, v.x, acc.x);
    acc.y = fmaf(w, v.y, acc.y);
    acc.z = fmaf(w, v.z, acc.z);
    acc.w = fmaf(w, v.w, acc.w);
    wsum += w;
  }
#pragma unroll
  for (int d = 16; d < 64; d <<= 1) {
    acc.x += __shfl_xor(acc.x, d);
    acc.y += __shfl_xor(acc.y, d);
    acc.z += __shfl_xor(acc.z, d);
    acc.w += __shfl_xor(acc.w, d);
    wsum  += __shfl_xor(wsum, d);
  }
  if (es == 0) {
    float inv = 1.f / fmaxf(wsum, 1e-8f);
    ((float4*)x2)[(size_t)wid * 16 + q] =
        make_float4(acc.x * inv, acc.y * inv, acc.z * inv, acc.w * inv);
  }
}

// ---------------------------------------------------------------------------
// K6: fused output head (per 64-node tile):
//   u3  = relu(x2@Wg + bg + t + bs)      (t = feat@Ws, precomputed)
//   emb = relu(u3@Wo + bo) + base
// ---------------------------------------------------------------------------
__global__ __launch_bounds__(256) void emb_kernel(const float* __restrict__ x2,
                                                  const float* __restrict__ tadd,
                                                  const float* __restrict__ Wg,
                                                  const float* __restrict__ Wo,
                                                  const float* __restrict__ bg,
                                                  const float* __restrict__ bs,
                                                  const float* __restrict__ bo,
                                                  const float* __restrict__ base,
                                                  float* __restrict__ emb, int M) {
  __shared__ float Xs[64][68];   // x2 transposed [k][m]; reused as u3 [n][m]
  __shared__ float Wgs[64][64];
  __shared__ float Wos[64][64];
  const int t  = threadIdx.x;
  const int tx = t & 15;
  const int ty = t >> 4;
  const int m0 = blockIdx.x * 64;

#pragma unroll
  for (int i = 0; i < 4; ++i) {
    int f = t + i * 256;
    int row = f >> 4, c4 = f & 15;
    int mg = m0 + row; mg = (mg < M) ? mg : (M - 1);
    float4 v = *(const float4*)(x2 + (size_t)mg * HDIM + c4 * 4);
    Xs[c4 * 4 + 0][row] = v.x;
    Xs[c4 * 4 + 1][row] = v.y;
    Xs[c4 * 4 + 2][row] = v.z;
    Xs[c4 * 4 + 3][row] = v.w;
    *(float4*)(&Wgs[row][c4 * 4]) = *(const float4*)(Wg + (size_t)row * HDIM + c4 * 4);
    *(float4*)(&Wos[row][c4 * 4]) = *(const float4*)(Wo + (size_t)row * HDIM + c4 * 4);
  }

  float4 bgv = *(const float4*)(bg + tx * 4);
  float4 bsv = *(const float4*)(bs + tx * 4);
  float acc[4][4];
#pragma unroll
  for (int i = 0; i < 4; ++i) {
    int mg = m0 + ty * 4 + i; mg = (mg < M) ? mg : (M - 1);
    float4 tv = *(const float4*)(tadd + (size_t)mg * HDIM + tx * 4);
    acc[i][0] = tv.x + bgv.x + bsv.x;
    acc[i][1] = tv.y + bgv.y + bsv.y;
    acc[i][2] = tv.z + bgv.z + bsv.z;
    acc[i][3] = tv.w + bgv.w + bsv.w;
  }
  __syncthreads();

#pragma unroll 4
  for (int k = 0; k < 64; ++k) {
    float4 a = *(const float4*)(&Xs[k][ty * 4]);
    float4 b = *(const float4*)(&Wgs[k][tx * 4]);
    acc[0][0] = fmaf(a.x, b.x, acc[0][0]);
    acc[0][1] = fmaf(a.x, b.y, acc[0][1]);
    acc[0][2] = fmaf(a.x, b.z, acc[0][2]);
    acc[0][3] = fmaf(a.x, b.w, acc[0][3]);
    acc[1][0] = fmaf(a.y, b.x, acc[1][0]);
    acc[1][1] = fmaf(a.y, b.y, acc[1][1]);
    acc[1][2] = fmaf(a.y, b.z, acc[1][2]);
    acc[1][3] = fmaf(a.y, b.w, acc[1][3]);
    acc[2][0] = fmaf(a.z, b.x, acc[2][0]);
    acc[2][1] = fmaf(a.z, b.y, acc[2][1]);
    acc[2][2] = fmaf(a.z, b.z, acc[2][2]);
    acc[2][3] = fmaf(a.z, b.w, acc[2][3]);
    acc[3][0] = fmaf(a.w, b.x, acc[3][0]);
    acc[3][1] = fmaf(a.w, b.y, acc[3][1]);
    acc[3][2] = fmaf(a.w, b.z, acc[3][2]);
    acc[3][3] = fmaf(a.w, b.w, acc[3][3]);
  }
  __syncthreads();

#pragma unroll
  for (int i = 0; i < 4; ++i)
#pragma unroll
    for (int j = 0; j < 4; ++j)
      Xs[tx * 4 + j][ty * 4 + i] = fmaxf(acc[i][j], 0.f);
  __syncthreads();

  float4 bov = *(const float4*)(bo + tx * 4);
  float acc2[4][4];
#pragma unroll
  for (int i = 0; i < 4; ++i) {
    acc2[i][0] = bov.x; acc2[i][1] = bov.y; acc2[i][2] = bov.z; acc2[i][3] = bov.w;
  }
#pragma unroll 4
  for (int k = 0; k < 64; ++k) {
    float4 a = *(const float4*)(&Xs[k][ty * 4]);
    float4 b = *(const float4*)(&Wos[k][tx * 4]);
    acc2[0][0] = fmaf(a.x, b.x, acc2[0][0]);
    acc2[0][1] = fmaf(a.x, b.y, acc2[0][1]);
    acc2[0][2] = fmaf(a.x, b.z, acc2[0][2]);
    acc2[0][3] = fmaf(a.x, b.w, acc2[0][3]);
    acc2[1][0] = fmaf(a.y, b.x, acc2[1][0]);
    acc2[1][1] = fmaf(a.y, b.y, acc2[1][1]);
    acc2[1][2] = fmaf(a.y, b.z, acc2[1][2]);
    acc2[1][3] = fmaf(a.y, b.w, acc2[1][3]);
    acc2[2][0] = fmaf(a.z, b.x, acc2[2][0]);
    acc2[2][1] = fmaf(a.z, b.y, acc2[2][1]);
    acc2[2][2] = fmaf(a.z, b.z, acc2[2][2]);
    acc2[2][3] = fmaf(a.z, b.w, acc2[2][3]);
    acc2[3][0] = fmaf(a.w, b.x, acc2[3][0]);
    acc2[3][1] = fmaf(a.w, b.y, acc2[3][1]);
    acc2[3][2] = fmaf(a.w, b.z, acc2[3][2]);
    acc2[3][3] = fmaf(a.w, b.w, acc2[3][3]);
  }

#pragma unroll
  for (int i = 0; i < 4; ++i) {
    int m = m0 + ty * 4 + i;
    if (m < M) {
      float4 bb = *(const float4*)(base + (size_t)m * HDIM + tx * 4);
      *(float4*)(emb + (size_t)m * HDIM + tx * 4) =
          make_float4(fmaxf(acc2[i][0], 0.f) + bb.x,
                      fmaxf(acc2[i][1], 0.f) + bb.y,
                      fmaxf(acc2[i][2], 0.f) + bb.z,
                      fmaxf(acc2[i][3], 0.f) + bb.w);
    }
  }
}

// ---------------------------------------------------------------------------
// K7: scoring — 4 pairs per wave, 16 lanes (float4 slices) per pair
// ---------------------------------------------------------------------------
__global__ void score_kernel(const int* __restrict__ uidx,
                             const int* __restrict__ bidx,
                             const float* __restrict__ uemb,
                             const float* __restrict__ bemb,
                             const float* __restrict__ ubias,
                             const float* __restrict__ bbias,
                             const float* __restrict__ gbias,
                             float* __restrict__ pred,
                             int batch) {
  int wave = (blockIdx.x * blockDim.x + threadIdx.x) >> 6;
  int lane = threadIdx.x & 63;
  int q = lane & 15, e = lane >> 4;
  int p = wave * 4 + e;            // BATCH_N % 4 == 0
  if (p >= batch) return;
  int u = uidx[p], b = bidx[p];
  float4 uv = ((const float4*)uemb)[(size_t)u * 16 + q];
  float4 bv = ((const float4*)bemb)[(size_t)b * 16 + q];
  float s = uv.x * bv.x + uv.y * bv.y + uv.z * bv.z + uv.w * bv.w;
#pragma unroll
  for (int d = 1; d < 16; d <<= 1) s += __shfl_xor(s, d);
  if (q == 0) {
    float sc = s + ubias[u] + bbias[b] + gbias[0];
    pred[p] = 4.f / (1.f + __expf(-sc)) + 1.f;
  }
}

// ---------------------------------------------------------------------------
extern "C" void kernel_launch(void* const* d_in, const int* in_sizes, int n_in,
                              void* d_out, int out_size, void* d_ws, size_t ws_size,
                              hipStream_t stream) {
  const float* uf    = (const float*)d_in[0];
  const float* bfeat = (const float*)d_in[1];
  const int*   ue    = (const int*)d_in[2];
  const int*   be    = (const int*)d_in[3];
  const int*   bet   = (const int*)d_in[4];
  const int*   uidx  = (const int*)d_in[5];
  const int*   bidx  = (const int*)d_in[6];
  const float* Wu    = (const float*)d_in[7];
  const float* Wb    = (const float*)d_in[8];
  const float* au    = (const float*)d_in[9];
  const float* ab    = (const float*)d_in[10];
  const float* gw    = (const float*)d_in[11];
  const float* Wug   = (const float*)d_in[12];
  const float* bug   = (const float*)d_in[13];
  const float* Wus   = (const float*)d_in[14];
  const float* bus   = (const float*)d_in[15];
  const float* Wbg   = (const float*)d_in[16];
  const float* bbg   = (const float*)d_in[17];
  const float* Wbs   = (const float*)d_in[18];
  const float* bbs   = (const float*)d_in[19];
  const float* Wuo   = (const float*)d_in[20];
  const float* buo   = (const float*)d_in[21];
  const float* Wbo   = (const float*)d_in[22];
  const float* bbo   = (const float*)d_in[23];
  const float* ubase = (const float*)d_in[24];
  const float* bbase = (const float*)d_in[25];
  const float* ubias = (const float*)d_in[26];
  const float* bbias = (const float*)d_in[27];
  const float* gbias = (const float*)d_in[28];

  // Workspace layout (4-byte units)
  float* W4 = (float*)d_ws;
  const size_t NH = (size_t)N_NODES * HDIM;  // 3,200,000
  float* u1     = W4;                        // x1 user; later t_u = uf@Wus
  float* b1     = W4 + NH;                   // x1 business; later t_b
  float* u2     = W4 + 2 * NH;
  float* b2     = W4 + 3 * NH;
  float* ssrc_u = W4 + 4 * NH;
  float* sdst_u = ssrc_u + N_NODES;
  float* ssrc_b = sdst_u + N_NODES;
  float* sdst_b = ssrc_b + N_NODES;
  int*   cnt    = (int*)(sdst_b + N_NODES);  // TOT2; reused as bump cursors
  int*   S      = cnt + TOT2;                // TOT2 + 1 segment starts
  int*   psum   = S + TOT2 + 4;              // S0B partials

  float* out      = (float*)d_out;
  float* out_pred = out;                     // BATCH_N
  float* out_uemb = out + BATCH_N;           // NH
  float* out_bemb = out + BATCH_N + NH;      // NH
  // Packed CSR records live in d_out's emb region (dead before emb_kernel).
  int* recbuf = (int*)(out + BATCH_N);       // 2*E_EDGES ints = 12.8 MB

  const int BLK = 256;
  const int tile_blocks = (N_NODES + 63) / 64;              // 782
  const int node_blocks = (N_NODES * 64 + BLK - 1) / BLK;   // wave per node
  const int edge_blocks = (E_EDGES + BLK - 1) / BLK;        // 6250
  const int pair_blocks = ((BATCH_N / 4) * 64 + BLK - 1) / BLK;  // 4 pairs/wave

  hipMemsetAsync(cnt, 0, TOT2 * sizeof(int), stream);

  // x1 = feat@W + fused attention scalars
  gemm_k256<<<tile_blocks, BLK, 0, stream>>>(uf, Wu, u1, N_NODES, au, ssrc_u, sdst_u);
  gemm_k256<<<tile_blocks, BLK, 0, stream>>>(bfeat, Wb, b1, N_NODES, ab, ssrc_b, sdst_b);

  edge_count2<<<dim3(edge_blocks, 2), BLK, 0, stream>>>((const int2*)ue, (const int2*)be, cnt);

  scan0<<<S0B, BLK, 0, stream>>>(cnt, psum);
  scan1<<<1, 128, 0, stream>>>(psum, S);
  scan2<<<(TOT2 + BLK - 1) / BLK, BLK, 0, stream>>>(cnt, S, psum);

  edge_pack_scatter<<<dim3(edge_blocks, 2), BLK, 0, stream>>>(
      (const int2*)ue, (const int2*)be, bet, cnt, recbuf);

  aggregate2<<<dim3(node_blocks, 2), BLK, 0, stream>>>(
      S, recbuf, ssrc_u, sdst_u, u1, u2, ssrc_b, sdst_b, b1, b2, gw);

  // t = feat@Ws, overwriting dead x1 buffers
  gemm_k256<<<tile_blocks, BLK, 0, stream>>>(uf, Wus, u1, N_NODES, nullptr, nullptr, nullptr);
  gemm_k256<<<tile_blocks, BLK, 0, stream>>>(bfeat, Wbs, b1, N_NODES, nullptr, nullptr, nullptr);

  // emb_kernel overwrites the recbuf region (recbuf is dead after aggregate2)
  emb_kernel<<<tile_blocks, BLK, 0, stream>>>(u2, u1, Wug, Wuo, bug, bus, buo,
                                              ubase, out_uemb, N_NODES);
  emb_kernel<<<tile_blocks, BLK, 0, stream>>>(b2, b1, Wbg, Wbo, bbg, bbs, bbo,
                                              bbase, out_bemb, N_NODES);

  score_kernel<<<pair_blocks, BLK, 0, stream>>>(uidx, bidx, out_uemb, out_bemb,
                                                ubias, bbias, gbias, out_pred, BATCH_N);
}